// Round 4
// baseline (2772.684 us; speedup 1.0000x reference)
//
#include <hip/hip_runtime.h>
#include <hip/hip_bf16.h>

#define D 128

typedef unsigned int u32;
typedef unsigned short ushort_t;
typedef __attribute__((ext_vector_type(8))) short short8;
typedef __attribute__((ext_vector_type(4))) float f32x4;

__device__ __forceinline__ float bf2f(ushort_t u){ return __uint_as_float(((u32)u)<<16); }
__device__ __forceinline__ ushort_t f2bf(float f){
  u32 x = __float_as_uint(f);
  return (ushort_t)((x + 0x7fffu + ((x>>16)&1u)) >> 16);
}
__device__ __forceinline__ float2 bfp2(u32 w){
  float2 r; r.x = __uint_as_float(w<<16); r.y = __uint_as_float(w & 0xffff0000u); return r;
}
__device__ __forceinline__ u32 packbf(float a, float b){
  return (u32)f2bf(a) | ((u32)f2bf(b)<<16);
}
__device__ __forceinline__ float sigm(float x){ return 1.0f/(1.0f+__expf(-x)); }
__device__ __forceinline__ float ftanh(float x){
  float e = __expf(-2.0f*fabsf(x));
  float t = (1.0f-e)/(1.0f+e);
  return copysignf(t,x);
}

// ---------------- dtype probe (f32 vs bf16 storage) ----------------
__global__ void detect_kernel(const u32* __restrict__ words, int* flag){
  int t = threadIdx.x;
  int cnt = 0;
  for (int i = t; i < 512; i += 64){
    u32 w = words[i];
    u32 e = (w >> 7) & 0xFFu;
    if (e >= 100u && e <= 126u) cnt++;
  }
  #pragma unroll
  for (int off = 32; off > 0; off >>= 1) cnt += __shfl_xor(cnt, off);
  if (t == 0) *flag = (cnt < 256) ? 1 : 0;
}

// ---------------- canonicalize all float inputs to bf16 ----------------
struct CvtArgs { const void* src[17]; ushort_t* dst[17]; int n[17]; };

__global__ __launch_bounds__(256) void convert_kernel(CvtArgs a, const int* __restrict__ flag){
  int isf = *flag;
  int gid = blockIdx.x*blockDim.x + threadIdx.x;
  int gs  = gridDim.x*blockDim.x;
  for (int s = 0; s < 17; s++){
    int n = a.n[s];
    ushort_t* dst = a.dst[s];
    if (isf){
      const float* src = (const float*)a.src[s];
      for (int j = gid; j < n; j += gs) dst[j] = f2bf(src[j]);
    } else {
      const ushort_t* src = (const ushort_t*)a.src[s];
      for (int j = gid; j < n; j += gs) dst[j] = src[j];
    }
  }
}

// ---------------- init ----------------
__global__ void init_kernel(float* agg, float* sum_exp, int* last_edge, int N){
  int i = blockIdx.x*blockDim.x + threadIdx.x;
  int stride = gridDim.x*blockDim.x;
  for (int j=i; j<N*D; j+=stride) agg[j]=0.f;
  for (int j=i; j<N;   j+=stride){ sum_exp[j]=0.f; last_edge[j]=-1; }
}

// ---------------- per-rel and per-query tables ----------------
__global__ void table_kernel(const ushort_t* __restrict__ rela,
  const ushort_t* __restrict__ Wz, const ushort_t* __restrict__ Wr, const ushort_t* __restrict__ Wh,
  const ushort_t* __restrict__ Wqr,
  const ushort_t* __restrict__ bz, const ushort_t* __restrict__ br, const ushort_t* __restrict__ bh,
  const ushort_t* __restrict__ bqr,
  const int* __restrict__ q_rel,
  ushort_t* hq_tab, ushort_t* Az, ushort_t* Ar, ushort_t* Ah,
  ushort_t* Bz, ushort_t* Br, ushort_t* Bh, ushort_t* Ca, int NRE, int NQ)
{
  __shared__ float hrow[D];
  int d = threadIdx.x;
  int b = blockIdx.x;
  if (b < NRE) {
    const ushort_t* row = rela + (size_t)b*D;
    hrow[d] = bf2f(row[d]);
    __syncthreads();
    float az=0.f, ar=0.f, ah=0.f;
    for (int k=0;k<D;k++){
      float h = hrow[k];
      az += h*bf2f(Wz[k*D+d]);
      ar += h*bf2f(Wr[k*D+d]);
      ah += h*bf2f(Wh[k*D+d]);
    }
    Az[b*D+d]=f2bf(az); Ar[b*D+d]=f2bf(ar); Ah[b*D+d]=f2bf(ah);
  } else {
    int q = b - NRE; if (q >= NQ) return;
    int rq = q_rel[q];
    const ushort_t* row = rela + (size_t)rq*D;
    hrow[d] = bf2f(row[d]);
    hq_tab[q*D+d] = row[d];
    __syncthreads();
    float vz=bf2f(bz[d]), vr=bf2f(br[d]), vh=bf2f(bh[d]), vc=bf2f(bqr[d]);
    for (int k=0;k<D;k++){
      float h = hrow[k];
      vz += h*bf2f(Wz[(D+k)*D+d]);
      vr += h*bf2f(Wr[(D+k)*D+d]);
      vh += h*bf2f(Wh[(D+k)*D+d]);
      vc += h*bf2f(Wqr[k*D+d]);
    }
    Bz[q*D+d]=f2bf(vz); Br[q*D+d]=f2bf(vr); Bh[q*D+d]=f2bf(vh); Ca[q*D+d]=f2bf(vc);
  }
}

// ---------------- HU = hidden @ Uz, hidden @ Ur ----------------
__global__ __launch_bounds__(256) void hu_kernel(const ushort_t* __restrict__ hidden,
  const ushort_t* __restrict__ Uz, const ushort_t* __restrict__ Ur,
  ushort_t* __restrict__ HUz, ushort_t* __restrict__ HUr, int N)
{
  int l = threadIdx.x & 63;
  int gw = (int)((blockIdx.x * blockDim.x + threadIdx.x) >> 6);
  int nw = (int)((gridDim.x * blockDim.x) >> 6);
  int c0 = 2*l;
  for (int n = gw; n < N; n += nw) {
    float2 h = bfp2(*(const u32*)(hidden + (size_t)n*D + c0));
    float az0=0.f,az1=0.f,ar0=0.f,ar1=0.f;
    #pragma unroll 4
    for (int kp=0; kp<64; kp++) {
      float hx = __shfl(h.x, kp);
      float hy = __shfl(h.y, kp);
      float2 uz0 = bfp2(*(const u32*)(Uz + (2*kp)*D + c0));
      float2 uz1 = bfp2(*(const u32*)(Uz + (2*kp+1)*D + c0));
      float2 ur0 = bfp2(*(const u32*)(Ur + (2*kp)*D + c0));
      float2 ur1 = bfp2(*(const u32*)(Ur + (2*kp+1)*D + c0));
      az0 += hx*uz0.x + hy*uz1.x;
      az1 += hx*uz0.y + hy*uz1.y;
      ar0 += hx*ur0.x + hy*ur1.x;
      ar1 += hx*ur0.y + hy*ur1.y;
    }
    *(u32*)(HUz + (size_t)n*D + c0) = packbf(az0, az1);
    *(u32*)(HUr + (size_t)n*D + c0) = packbf(ar0, ar1);
  }
}

// ---------------- fragment-order Uh and Ws for MFMA B-operand ----------------
// B-frag (16x16x32): lane holds B[k=(lane>>4)*8+j][n=lane&15], j contiguous.
// Array: [c(4 k-chunks)][t(8 col-tiles)][lane(64)][j(8)].
__global__ void fragorder_kernel(const ushort_t* __restrict__ Uh, const ushort_t* __restrict__ Ws,
                                 ushort_t* __restrict__ UhF, ushort_t* __restrict__ WsF){
  int idx = blockIdx.x*blockDim.x + threadIdx.x;
  if (idx >= 2*D*D) return;
  int which = idx >> 14;
  int i = idx & 16383;
  int j = i & 7;
  int l = (i >> 3) & 63;
  int ct = i >> 9;
  int c = ct >> 3, t = ct & 7;
  int k = c*32 + (l>>4)*8 + j;
  int n = t*16 + (l&15);
  ushort_t v = (which ? Ws : Uh)[k*D + n];
  if (which) WsF[i] = v; else UhF[i] = v;
}

// ---------------- main per-edge kernel (MFMA, A-layout direct gather) ----------------
// Wave owns 16 edges; lane (l15=l&15, q=l>>4) owns edge l15, cols c*32+q*8+{0..7}.
// All elementwise state lives in A-fragment layout registers; only AC/ATT
// round-trip C/D->A through wave-private LDS.
__global__ __launch_bounds__(256, 3) void edge_kernel(
  const int* __restrict__ edges,
  const ushort_t* __restrict__ hidden,
  const ushort_t* __restrict__ HUz, const ushort_t* __restrict__ HUr,
  const ushort_t* __restrict__ Az, const ushort_t* __restrict__ Ar, const ushort_t* __restrict__ Ah,
  const ushort_t* __restrict__ Bz, const ushort_t* __restrict__ Br, const ushort_t* __restrict__ Bh,
  const ushort_t* __restrict__ Ca,
  const ushort_t* __restrict__ UhF, const ushort_t* __restrict__ WsF,
  const ushort_t* __restrict__ w_alpha, const ushort_t* __restrict__ b_alpha,
  float* __restrict__ agg, float* __restrict__ sum_exp, int* __restrict__ last_edge,
  int E)
{
  __shared__ __align__(16) ushort_t vm[4][16*136];   // 17.4KB total, wave-private
  int tid = threadIdx.x;
  int w = tid>>6, l = tid&63;
  int l15 = l & 15, q = l >> 4;
  ushort_t* vw = &vm[w][0];
  float bal = bf2f(b_alpha[0]);

  int nIter = (E + 63) >> 6;
  for (int it = blockIdx.x; it < nIter; it += gridDim.x) {
    int eraw = it*64 + w*16 + l15;
    int eg = (eraw < E) ? eraw : (E-1);
    bool valid = (eraw < E);
    const int* ep = edges + (size_t)eg*6;
    int ridx = ep[0], rel = ep[2], sub = ep[4], obj = ep[5];
    const ushort_t* pAz = Az + (size_t)rel*D;
    const ushort_t* pAr = Ar + (size_t)rel*D;
    const ushort_t* pBz = Bz + (size_t)ridx*D;
    const ushort_t* pBr = Br + (size_t)ridx*D;
    const ushort_t* pHz = HUz + (size_t)sub*D;
    const ushort_t* pHr = HUr + (size_t)sub*D;
    const ushort_t* pHs = hidden + (size_t)sub*D;

    u32 zp[16], hp[16];
    short8 af[4];
    // ---- gather directly in A-layout: z, hs kept; af = r*hs ----
    #pragma unroll
    for (int c=0;c<4;c++){
      int off = c*32 + q*8;
      short8 vaz = *(const short8*)(pAz + off);
      short8 vbz = *(const short8*)(pBz + off);
      short8 vhz = *(const short8*)(pHz + off);
      short8 var_ = *(const short8*)(pAr + off);
      short8 vbr = *(const short8*)(pBr + off);
      short8 vhr = *(const short8*)(pHr + off);
      short8 vhs = *(const short8*)(pHs + off);
      const u32* az4 = (const u32*)&vaz; const u32* bz4 = (const u32*)&vbz;
      const u32* hz4 = (const u32*)&vhz; const u32* ar4 = (const u32*)&var_;
      const u32* br4 = (const u32*)&vbr; const u32* hr4 = (const u32*)&vhr;
      const u32* hs4 = (const u32*)&vhs;
      u32 vv[4];
      #pragma unroll
      for (int jj=0;jj<4;jj++){
        float2 a2 = bfp2(az4[jj]), b2 = bfp2(bz4[jj]), h2 = bfp2(hz4[jj]);
        float z0 = sigm(a2.x+b2.x+h2.x), z1 = sigm(a2.y+b2.y+h2.y);
        float2 ra = bfp2(ar4[jj]), rb = bfp2(br4[jj]), rh = bfp2(hr4[jj]);
        float r0 = sigm(ra.x+rb.x+rh.x), r1 = sigm(ra.y+rb.y+rh.y);
        float2 hs2 = bfp2(hs4[jj]);
        zp[c*4+jj] = packbf(z0,z1);
        hp[c*4+jj] = hs4[jj];
        vv[jj] = packbf(r0*hs2.x, r1*hs2.y);
      }
      af[c] = *(short8*)vv;
    }
    // ---- matvec1: AC[16x128] = (r*hs) @ Uh ----
    f32x4 zero = {0.f,0.f,0.f,0.f};
    f32x4 acc[8];
    #pragma unroll
    for (int t=0;t<8;t++) acc[t] = zero;
    #pragma unroll
    for (int t=0;t<8;t++){
      #pragma unroll
      for (int c=0;c<4;c++){
        short8 bf = *(const short8*)(UhF + ((size_t)((c*8+t)*64 + l))*8);
        acc[t] = __builtin_amdgcn_mfma_f32_16x16x32_bf16(af[c], bf, acc[t], 0,0,0);
      }
    }
    // ---- transpose AC: C/D -> A layout via LDS ----
    __builtin_amdgcn_wave_barrier();
    #pragma unroll
    for (int t=0;t<8;t++){
      #pragma unroll
      for (int r=0;r<4;r++){
        float x = acc[t][r];
        float y = __shfl_xor(x, 1);
        if (!(l & 1))
          *(u32*)(vw + (q*4+r)*136 + t*16 + l15) = packbf(x, y);
      }
    }
    // regather ab = Ah[rel]+Bh[ridx] (L2-hot small tables)
    short8 ah8[4], bh8[4];
    #pragma unroll
    for (int c=0;c<4;c++){
      ah8[c] = *(const short8*)(Ah + (size_t)rel*D + c*32 + q*8);
      bh8[c] = *(const short8*)(Bh + (size_t)ridx*D + c*32 + q*8);
    }
    __builtin_amdgcn_wave_barrier();
    // ---- gate: m = (1-z)*hs + z*tanh(ac+ab); af <- m (packed) ----
    #pragma unroll
    for (int c=0;c<4;c++){
      short8 acv = *(const short8*)(vw + l15*136 + c*32 + q*8);
      const u32* ac4 = (const u32*)&acv;
      const u32* ah4 = (const u32*)&ah8[c];
      const u32* bh4 = (const u32*)&bh8[c];
      u32 mv[4];
      #pragma unroll
      for (int jj=0;jj<4;jj++){
        float2 ac2 = bfp2(ac4[jj]);
        float2 a2 = bfp2(ah4[jj]), b2 = bfp2(bh4[jj]);
        float2 z2 = bfp2(zp[c*4+jj]);
        float2 h2 = bfp2(hp[c*4+jj]);
        float m0 = (1.f - z2.x)*h2.x + z2.x*ftanh(ac2.x + a2.x + b2.x);
        float m1 = (1.f - z2.y)*h2.y + z2.y*ftanh(ac2.y + a2.y + b2.y);
        mv[jj] = packbf(m0, m1);
      }
      af[c] = *(short8*)mv;
    }
    // ---- matvec2: ATT[16x128] = M @ Ws ----
    #pragma unroll
    for (int t=0;t<8;t++) acc[t] = zero;
    #pragma unroll
    for (int t=0;t<8;t++){
      #pragma unroll
      for (int c=0;c<4;c++){
        short8 bf = *(const short8*)(WsF + ((size_t)((c*8+t)*64 + l))*8);
        acc[t] = __builtin_amdgcn_mfma_f32_16x16x32_bf16(af[c], bf, acc[t], 0,0,0);
      }
    }
    // ---- transpose ATT: C/D -> A layout via LDS ----
    __builtin_amdgcn_wave_barrier();
    #pragma unroll
    for (int t=0;t<8;t++){
      #pragma unroll
      for (int r=0;r<4;r++){
        float x = acc[t][r];
        float y = __shfl_xor(x, 1);
        if (!(l & 1))
          *(u32*)(vw + (q*4+r)*136 + t*16 + l15) = packbf(x, y);
      }
    }
    short8 ca8[4], wa8[4];
    #pragma unroll
    for (int c=0;c<4;c++){
      ca8[c] = *(const short8*)(Ca + (size_t)ridx*D + c*32 + q*8);
      wa8[c] = *(const short8*)(w_alpha + c*32 + q*8);
    }
    __builtin_amdgcn_wave_barrier();
    // ---- attn score: s = sum relu(att+ca)*w_alpha over lane's 32 cols ----
    float s = 0.f;
    #pragma unroll
    for (int c=0;c<4;c++){
      short8 atv = *(const short8*)(vw + l15*136 + c*32 + q*8);
      const u32* at4 = (const u32*)&atv;
      const u32* ca4 = (const u32*)&ca8[c];
      const u32* wa4 = (const u32*)&wa8[c];
      #pragma unroll
      for (int jj=0;jj<4;jj++){
        float2 a2 = bfp2(at4[jj]);
        float2 c2 = bfp2(ca4[jj]);
        float2 w2 = bfp2(wa4[jj]);
        s += fmaxf(a2.x + c2.x, 0.f)*w2.x + fmaxf(a2.y + c2.y, 0.f)*w2.y;
      }
    }
    s += __shfl_xor(s, 16);
    s += __shfl_xor(s, 32);
    float ea = __expf(s + bal);
    // ---- scatter ----
    if (valid){
      float* ap = agg + (size_t)obj*D + q*8;
      #pragma unroll
      for (int c=0;c<4;c++){
        const u32* m4 = (const u32*)&af[c];
        #pragma unroll
        for (int jj=0;jj<4;jj++){
          float2 m2 = bfp2(m4[jj]);
          atomicAdd(ap + c*32 + 2*jj,     ea*m2.x);
          atomicAdd(ap + c*32 + 2*jj + 1, ea*m2.y);
        }
      }
      if (q == 0){
        atomicAdd(sum_exp + obj, ea);
        atomicMax(last_edge + obj, eg);
      }
    }
  }
}

// ---------------- finalize (4-node batched, dual output format) ----------------
__global__ __launch_bounds__(256) void final_kernel(
  const float* __restrict__ agg, const float* __restrict__ sum_exp,
  const int* __restrict__ last_edge, const int* __restrict__ edges,
  const ushort_t* __restrict__ hq_tab, const ushort_t* __restrict__ Wh,
  const int* __restrict__ flag, void* __restrict__ out_base, int N)
{
  __shared__ float mb[4][D][4];
  int tid = threadIdx.x, w = tid >> 6, l = tid & 63;
  int c0 = 2*l, c1 = c0+1;
  int isf = *flag;
  float* out0f = (float*)out_base;
  float* out1f = out0f + (size_t)N*D;
  ushort_t* out0h = (ushort_t*)out_base;
  ushort_t* out1h = out0h + (size_t)N*D;
  int nIter = (N + 15) >> 4;
  for (int it = blockIdx.x; it < nIter; it += gridDim.x){
    int base = it*16 + w*4;
    int rq[4];
    #pragma unroll
    for (int e=0;e<4;e++){
      int n = base + e; if (n >= N) n = N-1;
      float se = sum_exp[n];
      float inv = (se > 0.f) ? (1.0f/se) : 0.f;
      float2 m = *(const float2*)(agg + (size_t)n*D + c0);
      mb[w][c0][e] = m.x*inv; mb[w][c1][e] = m.y*inv;
      int le = last_edge[n];
      rq[e] = (le >= 0) ? edges[(size_t)le*6] : 0;
    }
    float a0[4] = {0,0,0,0}, a1[4] = {0,0,0,0};
    #pragma unroll 4
    for (int kp=0; kp<64; kp++){
      float4 ma = *(float4*)&mb[w][2*kp][0];
      float4 mv = *(float4*)&mb[w][2*kp+1][0];
      float2 u0 = bfp2(*(const u32*)(Wh + (2*kp)*D + c0));
      float2 u1 = bfp2(*(const u32*)(Wh + (2*kp+1)*D + c0));
      a0[0] += ma.x*u0.x + mv.x*u1.x;  a1[0] += ma.x*u0.y + mv.x*u1.y;
      a0[1] += ma.y*u0.x + mv.y*u1.x;  a1[1] += ma.y*u0.y + mv.y*u1.y;
      a0[2] += ma.z*u0.x + mv.z*u1.x;  a1[2] += ma.z*u0.y + mv.z*u1.y;
      a0[3] += ma.w*u0.x + mv.w*u1.x;  a1[3] += ma.w*u0.y + mv.w*u1.y;
    }
    #pragma unroll
    for (int e=0;e<4;e++){
      int n = base + e; if (n >= N) continue;
      float r0 = fmaxf(a0[e], 0.f), r1 = fmaxf(a1[e], 0.f);
      u32 hqw = *(const u32*)(hq_tab + (size_t)rq[e]*D + c0);
      if (isf){
        float2 o0; o0.x = r0; o0.y = r1;
        *(float2*)(out0f + (size_t)n*D + c0) = o0;
        float2 hv = bfp2(hqw);
        *(float2*)(out1f + (size_t)n*D + c0) = hv;
      } else {
        *(u32*)(out0h + (size_t)n*D + c0) = packbf(r0, r1);
        *(u32*)(out1h + (size_t)n*D + c0) = hqw;
      }
    }
  }
}

extern "C" void kernel_launch(void* const* d_in, const int* in_sizes, int n_in,
                              void* d_out, int out_size, void* d_ws, size_t ws_size,
                              hipStream_t stream)
{
  const int* q_rel = (const int*)d_in[17];
  const int* edges = (const int*)d_in[18];

  int N   = in_sizes[0]/D;
  int NRE = in_sizes[1]/D;
  int NQ  = in_sizes[17];
  int E   = in_sizes[18]/6;

  char* ws = (char*)d_ws;
  size_t o = 0;
  auto alloc = [&](size_t bytes)->void*{
    void* p = ws + o; o += (bytes + 255) & ~(size_t)255; return p;
  };
  float* agg      = (float*)alloc((size_t)N*D*4);
  float* sum_exp  = (float*)alloc((size_t)N*4);
  int*   lastedge = (int*)  alloc((size_t)N*4);
  int*   flag     = (int*)  alloc(256);

  ushort_t* canon[17];
  for (int i=0;i<17;i++) canon[i] = (ushort_t*)alloc((size_t)in_sizes[i]*2);

  ushort_t* hq_tab = (ushort_t*)alloc((size_t)NQ*D*2);
  ushort_t* Az = (ushort_t*)alloc((size_t)NRE*D*2);
  ushort_t* Ar = (ushort_t*)alloc((size_t)NRE*D*2);
  ushort_t* Ah = (ushort_t*)alloc((size_t)NRE*D*2);
  ushort_t* Bz = (ushort_t*)alloc((size_t)NQ*D*2);
  ushort_t* Br = (ushort_t*)alloc((size_t)NQ*D*2);
  ushort_t* Bh = (ushort_t*)alloc((size_t)NQ*D*2);
  ushort_t* Ca = (ushort_t*)alloc((size_t)NQ*D*2);
  ushort_t* HUz = (ushort_t*)alloc((size_t)N*D*2);
  ushort_t* HUr = (ushort_t*)alloc((size_t)N*D*2);
  ushort_t* UhF = (ushort_t*)alloc((size_t)D*D*2);
  ushort_t* WsF = (ushort_t*)alloc((size_t)D*D*2);

  CvtArgs ca;
  for (int i=0;i<17;i++){ ca.src[i]=d_in[i]; ca.dst[i]=canon[i]; ca.n[i]=in_sizes[i]; }

  const ushort_t* hidden = canon[0];
  const ushort_t* rela   = canon[1];
  const ushort_t* Wz  = canon[2];
  const ushort_t* Uz  = canon[3];
  const ushort_t* bz  = canon[4];
  const ushort_t* Wr  = canon[5];
  const ushort_t* Ur  = canon[6];
  const ushort_t* br  = canon[7];
  const ushort_t* Whh = canon[8];
  const ushort_t* Uh  = canon[9];
  const ushort_t* bh  = canon[10];
  const ushort_t* Ws  = canon[11];
  const ushort_t* Wqr = canon[12];
  const ushort_t* bqr = canon[13];
  const ushort_t* wal = canon[14];
  const ushort_t* bal = canon[15];
  const ushort_t* W_h = canon[16];

  detect_kernel<<<1, 64, 0, stream>>>((const u32*)d_in[1], flag);
  convert_kernel<<<1024, 256, 0, stream>>>(ca, flag);
  init_kernel<<<4096, 256, 0, stream>>>(agg, sum_exp, lastedge, N);
  fragorder_kernel<<<128, 256, 0, stream>>>(Uh, Ws, UhF, WsF);
  table_kernel<<<NRE+NQ, 128, 0, stream>>>(rela, Wz, Wr, Whh, Wqr, bz, br, bh, bqr,
                                           q_rel, hq_tab, Az, Ar, Ah, Bz, Br, Bh, Ca, NRE, NQ);
  hu_kernel<<<1024, 256, 0, stream>>>(hidden, Uz, Ur, HUz, HUr, N);
  edge_kernel<<<2048, 256, 0, stream>>>(edges, hidden, HUz, HUr, Az, Ar, Ah, Bz, Br, Bh, Ca,
                                        UhF, WsF, wal, bal, agg, sum_exp, lastedge, E);
  final_kernel<<<1024, 256, 0, stream>>>(agg, sum_exp, lastedge, edges, hq_tab, W_h,
                                         flag, d_out, N);
}

// Round 5
// 1560.401 us; speedup vs baseline: 1.7769x; 1.7769x over previous
//
#include <hip/hip_runtime.h>
#include <hip/hip_bf16.h>

#define D 128

typedef unsigned int u32;
typedef unsigned short ushort_t;
typedef __attribute__((ext_vector_type(8))) short short8;
typedef __attribute__((ext_vector_type(4))) float f32x4;

__device__ __forceinline__ float bf2f(ushort_t u){ return __uint_as_float(((u32)u)<<16); }
__device__ __forceinline__ ushort_t f2bf(float f){
  u32 x = __float_as_uint(f);
  return (ushort_t)((x + 0x7fffu + ((x>>16)&1u)) >> 16);
}
__device__ __forceinline__ float2 bfp2(u32 w){
  float2 r; r.x = __uint_as_float(w<<16); r.y = __uint_as_float(w & 0xffff0000u); return r;
}
__device__ __forceinline__ u32 packbf(float a, float b){
  return (u32)f2bf(a) | ((u32)f2bf(b)<<16);
}
__device__ __forceinline__ float sigm(float x){ return 1.0f/(1.0f+__expf(-x)); }
__device__ __forceinline__ float ftanh(float x){
  float e = __expf(-2.0f*fabsf(x));
  float t = (1.0f-e)/(1.0f+e);
  return copysignf(t,x);
}

// ---------------- dtype probe (f32 vs bf16 storage) ----------------
__global__ void detect_kernel(const u32* __restrict__ words, int* flag){
  int t = threadIdx.x;
  int cnt = 0;
  for (int i = t; i < 512; i += 64){
    u32 w = words[i];
    u32 e = (w >> 7) & 0xFFu;
    if (e >= 100u && e <= 126u) cnt++;
  }
  #pragma unroll
  for (int off = 32; off > 0; off >>= 1) cnt += __shfl_xor(cnt, off);
  if (t == 0) *flag = (cnt < 256) ? 1 : 0;
}

// ---------------- canonicalize all float inputs to bf16 ----------------
struct CvtArgs { const void* src[17]; ushort_t* dst[17]; int n[17]; };

__global__ __launch_bounds__(256) void convert_kernel(CvtArgs a, const int* __restrict__ flag){
  int isf = *flag;
  int gid = blockIdx.x*blockDim.x + threadIdx.x;
  int gs  = gridDim.x*blockDim.x;
  for (int s = 0; s < 17; s++){
    int n = a.n[s];
    ushort_t* dst = a.dst[s];
    if (isf){
      const float* src = (const float*)a.src[s];
      for (int j = gid; j < n; j += gs) dst[j] = f2bf(src[j]);
    } else {
      const ushort_t* src = (const ushort_t*)a.src[s];
      for (int j = gid; j < n; j += gs) dst[j] = src[j];
    }
  }
}

// ---------------- init ----------------
__global__ void init_kernel(float* agg, float* sum_exp, int* last_edge, int N){
  int i = blockIdx.x*blockDim.x + threadIdx.x;
  int stride = gridDim.x*blockDim.x;
  for (int j=i; j<N*D; j+=stride) agg[j]=0.f;
  for (int j=i; j<N;   j+=stride){ sum_exp[j]=0.f; last_edge[j]=-1; }
}

// ---------------- per-rel and per-query tables ----------------
__global__ void table_kernel(const ushort_t* __restrict__ rela,
  const ushort_t* __restrict__ Wz, const ushort_t* __restrict__ Wr, const ushort_t* __restrict__ Wh,
  const ushort_t* __restrict__ Wqr,
  const ushort_t* __restrict__ bz, const ushort_t* __restrict__ br, const ushort_t* __restrict__ bh,
  const ushort_t* __restrict__ bqr,
  const int* __restrict__ q_rel,
  ushort_t* hq_tab, ushort_t* Az, ushort_t* Ar, ushort_t* Ah,
  ushort_t* Bz, ushort_t* Br, ushort_t* Bh, ushort_t* Ca, int NRE, int NQ)
{
  __shared__ float hrow[D];
  int d = threadIdx.x;
  int b = blockIdx.x;
  if (b < NRE) {
    const ushort_t* row = rela + (size_t)b*D;
    hrow[d] = bf2f(row[d]);
    __syncthreads();
    float az=0.f, ar=0.f, ah=0.f;
    for (int k=0;k<D;k++){
      float h = hrow[k];
      az += h*bf2f(Wz[k*D+d]);
      ar += h*bf2f(Wr[k*D+d]);
      ah += h*bf2f(Wh[k*D+d]);
    }
    Az[b*D+d]=f2bf(az); Ar[b*D+d]=f2bf(ar); Ah[b*D+d]=f2bf(ah);
  } else {
    int q = b - NRE; if (q >= NQ) return;
    int rq = q_rel[q];
    const ushort_t* row = rela + (size_t)rq*D;
    hrow[d] = bf2f(row[d]);
    hq_tab[q*D+d] = row[d];
    __syncthreads();
    float vz=bf2f(bz[d]), vr=bf2f(br[d]), vh=bf2f(bh[d]), vc=bf2f(bqr[d]);
    for (int k=0;k<D;k++){
      float h = hrow[k];
      vz += h*bf2f(Wz[(D+k)*D+d]);
      vr += h*bf2f(Wr[(D+k)*D+d]);
      vh += h*bf2f(Wh[(D+k)*D+d]);
      vc += h*bf2f(Wqr[k*D+d]);
    }
    Bz[q*D+d]=f2bf(vz); Br[q*D+d]=f2bf(vr); Bh[q*D+d]=f2bf(vh); Ca[q*D+d]=f2bf(vc);
  }
}

// ---------------- HU = hidden @ Uz, hidden @ Ur ----------------
__global__ __launch_bounds__(256) void hu_kernel(const ushort_t* __restrict__ hidden,
  const ushort_t* __restrict__ Uz, const ushort_t* __restrict__ Ur,
  ushort_t* __restrict__ HUz, ushort_t* __restrict__ HUr, int N)
{
  int l = threadIdx.x & 63;
  int gw = (int)((blockIdx.x * blockDim.x + threadIdx.x) >> 6);
  int nw = (int)((gridDim.x * blockDim.x) >> 6);
  int c0 = 2*l;
  for (int n = gw; n < N; n += nw) {
    float2 h = bfp2(*(const u32*)(hidden + (size_t)n*D + c0));
    float az0=0.f,az1=0.f,ar0=0.f,ar1=0.f;
    #pragma unroll 4
    for (int kp=0; kp<64; kp++) {
      float hx = __shfl(h.x, kp);
      float hy = __shfl(h.y, kp);
      float2 uz0 = bfp2(*(const u32*)(Uz + (2*kp)*D + c0));
      float2 uz1 = bfp2(*(const u32*)(Uz + (2*kp+1)*D + c0));
      float2 ur0 = bfp2(*(const u32*)(Ur + (2*kp)*D + c0));
      float2 ur1 = bfp2(*(const u32*)(Ur + (2*kp+1)*D + c0));
      az0 += hx*uz0.x + hy*uz1.x;
      az1 += hx*uz0.y + hy*uz1.y;
      ar0 += hx*ur0.x + hy*ur1.x;
      ar1 += hx*ur0.y + hy*ur1.y;
    }
    *(u32*)(HUz + (size_t)n*D + c0) = packbf(az0, az1);
    *(u32*)(HUr + (size_t)n*D + c0) = packbf(ar0, ar1);
  }
}

// ---------------- fragment-order Uh and Ws for MFMA B-operand ----------------
// B-frag (16x16x32): lane holds B[k=(lane>>4)*8+j][n=lane&15], j contiguous.
// Array: [c(4 k-chunks)][t(8 col-tiles)][lane(64)][j(8)].
__global__ void fragorder_kernel(const ushort_t* __restrict__ Uh, const ushort_t* __restrict__ Ws,
                                 ushort_t* __restrict__ UhF, ushort_t* __restrict__ WsF){
  int idx = blockIdx.x*blockDim.x + threadIdx.x;
  if (idx >= 2*D*D) return;
  int which = idx >> 14;
  int i = idx & 16383;
  int j = i & 7;
  int l = (i >> 3) & 63;
  int ct = i >> 9;
  int c = ct >> 3, t = ct & 7;
  int k = c*32 + (l>>4)*8 + j;
  int n = t*16 + (l&15);
  ushort_t v = (which ? Ws : Uh)[k*D + n];
  if (which) WsF[i] = v; else UhF[i] = v;
}

// ---------------- main per-edge kernel (MFMA, A-layout gather, row-uniform scatter) ----------------
// Wave owns 16 edges; lane (l15=l&15, q=l>>4) owns edge l15, cols c*32+q*8+{0..7}.
// Elementwise state in A-frag registers; AC/ATT round-trip C/D->A via LDS (vw);
// m staged in a second LDS buffer (mw) so the atomic scatter can be row-uniform
// (64 lanes contiguous on one obj row per atomic instruction — R2's proven pattern).
__global__ __launch_bounds__(256, 4) void edge_kernel(
  const int* __restrict__ edges,
  const ushort_t* __restrict__ hidden,
  const ushort_t* __restrict__ HUz, const ushort_t* __restrict__ HUr,
  const ushort_t* __restrict__ Az, const ushort_t* __restrict__ Ar, const ushort_t* __restrict__ Ah,
  const ushort_t* __restrict__ Bz, const ushort_t* __restrict__ Br, const ushort_t* __restrict__ Bh,
  const ushort_t* __restrict__ Ca,
  const ushort_t* __restrict__ UhF, const ushort_t* __restrict__ WsF,
  const ushort_t* __restrict__ w_alpha, const ushort_t* __restrict__ b_alpha,
  float* __restrict__ agg, float* __restrict__ sum_exp, int* __restrict__ last_edge,
  int E)
{
  __shared__ __align__(16) ushort_t vm[4][16*136];   // transpose scratch
  __shared__ __align__(16) ushort_t mm[4][16*136];   // m in edge-row layout
  int tid = threadIdx.x;
  int w = tid>>6, l = tid&63;
  int l15 = l & 15, q = l >> 4;
  int c0 = 2*l;
  ushort_t* vw = &vm[w][0];
  ushort_t* mw = &mm[w][0];
  float bal = bf2f(b_alpha[0]);

  int nIter = (E + 63) >> 6;
  for (int it = blockIdx.x; it < nIter; it += gridDim.x) {
    int eraw = it*64 + w*16 + l15;
    int eg = (eraw < E) ? eraw : (E-1);
    const int* ep = edges + (size_t)eg*6;
    int ridx = ep[0], rel = ep[2], sub = ep[4], obj = ep[5];
    const ushort_t* pAz = Az + (size_t)rel*D;
    const ushort_t* pAr = Ar + (size_t)rel*D;
    const ushort_t* pBz = Bz + (size_t)ridx*D;
    const ushort_t* pBr = Br + (size_t)ridx*D;
    const ushort_t* pHz = HUz + (size_t)sub*D;
    const ushort_t* pHr = HUr + (size_t)sub*D;
    const ushort_t* pHs = hidden + (size_t)sub*D;

    u32 zp[16], hp[16];
    short8 af[4];
    // ---- gather directly in A-layout: z, hs kept; af = r*hs ----
    #pragma unroll
    for (int c=0;c<4;c++){
      int off = c*32 + q*8;
      short8 vaz = *(const short8*)(pAz + off);
      short8 vbz = *(const short8*)(pBz + off);
      short8 vhz = *(const short8*)(pHz + off);
      short8 var_ = *(const short8*)(pAr + off);
      short8 vbr = *(const short8*)(pBr + off);
      short8 vhr = *(const short8*)(pHr + off);
      short8 vhs = *(const short8*)(pHs + off);
      const u32* az4 = (const u32*)&vaz; const u32* bz4 = (const u32*)&vbz;
      const u32* hz4 = (const u32*)&vhz; const u32* ar4 = (const u32*)&var_;
      const u32* br4 = (const u32*)&vbr; const u32* hr4 = (const u32*)&vhr;
      const u32* hs4 = (const u32*)&vhs;
      u32 vv[4];
      #pragma unroll
      for (int jj=0;jj<4;jj++){
        float2 a2 = bfp2(az4[jj]), b2 = bfp2(bz4[jj]), h2 = bfp2(hz4[jj]);
        float z0 = sigm(a2.x+b2.x+h2.x), z1 = sigm(a2.y+b2.y+h2.y);
        float2 ra = bfp2(ar4[jj]), rb = bfp2(br4[jj]), rh = bfp2(hr4[jj]);
        float r0 = sigm(ra.x+rb.x+rh.x), r1 = sigm(ra.y+rb.y+rh.y);
        float2 hs2 = bfp2(hs4[jj]);
        zp[c*4+jj] = packbf(z0,z1);
        hp[c*4+jj] = hs4[jj];
        vv[jj] = packbf(r0*hs2.x, r1*hs2.y);
      }
      af[c] = *(short8*)vv;
    }
    // ---- matvec1: AC[16x128] = (r*hs) @ Uh ----
    f32x4 zero = {0.f,0.f,0.f,0.f};
    f32x4 acc[8];
    #pragma unroll
    for (int t=0;t<8;t++) acc[t] = zero;
    #pragma unroll
    for (int t=0;t<8;t++){
      #pragma unroll
      for (int c=0;c<4;c++){
        short8 bf = *(const short8*)(UhF + ((size_t)((c*8+t)*64 + l))*8);
        acc[t] = __builtin_amdgcn_mfma_f32_16x16x32_bf16(af[c], bf, acc[t], 0,0,0);
      }
    }
    // ---- transpose AC: C/D -> A layout via LDS ----
    __builtin_amdgcn_wave_barrier();
    #pragma unroll
    for (int t=0;t<8;t++){
      #pragma unroll
      for (int r=0;r<4;r++){
        float x = acc[t][r];
        float y = __shfl_xor(x, 1);
        if (!(l & 1))
          *(u32*)(vw + (q*4+r)*136 + t*16 + l15) = packbf(x, y);
      }
    }
    // regather ab = Ah[rel]+Bh[ridx] (L2-hot small tables)
    short8 ah8[4], bh8[4];
    #pragma unroll
    for (int c=0;c<4;c++){
      ah8[c] = *(const short8*)(Ah + (size_t)rel*D + c*32 + q*8);
      bh8[c] = *(const short8*)(Bh + (size_t)ridx*D + c*32 + q*8);
    }
    __builtin_amdgcn_wave_barrier();
    // ---- gate: m = (1-z)*hs + z*tanh(ac+ab); af <- m; m also to mw (edge-row) ----
    #pragma unroll
    for (int c=0;c<4;c++){
      short8 acv = *(const short8*)(vw + l15*136 + c*32 + q*8);
      const u32* ac4 = (const u32*)&acv;
      const u32* ah4 = (const u32*)&ah8[c];
      const u32* bh4 = (const u32*)&bh8[c];
      u32 mv[4];
      #pragma unroll
      for (int jj=0;jj<4;jj++){
        float2 ac2 = bfp2(ac4[jj]);
        float2 a2 = bfp2(ah4[jj]), b2 = bfp2(bh4[jj]);
        float2 z2 = bfp2(zp[c*4+jj]);
        float2 h2 = bfp2(hp[c*4+jj]);
        float m0 = (1.f - z2.x)*h2.x + z2.x*ftanh(ac2.x + a2.x + b2.x);
        float m1 = (1.f - z2.y)*h2.y + z2.y*ftanh(ac2.y + a2.y + b2.y);
        mv[jj] = packbf(m0, m1);
      }
      af[c] = *(short8*)mv;
      *(short8*)(mw + l15*136 + c*32 + q*8) = af[c];
    }
    // ---- matvec2: ATT[16x128] = M @ Ws ----
    #pragma unroll
    for (int t=0;t<8;t++) acc[t] = zero;
    #pragma unroll
    for (int t=0;t<8;t++){
      #pragma unroll
      for (int c=0;c<4;c++){
        short8 bf = *(const short8*)(WsF + ((size_t)((c*8+t)*64 + l))*8);
        acc[t] = __builtin_amdgcn_mfma_f32_16x16x32_bf16(af[c], bf, acc[t], 0,0,0);
      }
    }
    // ---- transpose ATT: C/D -> A layout via LDS ----
    __builtin_amdgcn_wave_barrier();
    #pragma unroll
    for (int t=0;t<8;t++){
      #pragma unroll
      for (int r=0;r<4;r++){
        float x = acc[t][r];
        float y = __shfl_xor(x, 1);
        if (!(l & 1))
          *(u32*)(vw + (q*4+r)*136 + t*16 + l15) = packbf(x, y);
      }
    }
    short8 ca8[4], wa8[4];
    #pragma unroll
    for (int c=0;c<4;c++){
      ca8[c] = *(const short8*)(Ca + (size_t)ridx*D + c*32 + q*8);
      wa8[c] = *(const short8*)(w_alpha + c*32 + q*8);
    }
    __builtin_amdgcn_wave_barrier();
    // ---- attn score: s = sum relu(att+ca)*w_alpha over lane's 32 cols ----
    float s = 0.f;
    #pragma unroll
    for (int c=0;c<4;c++){
      short8 atv = *(const short8*)(vw + l15*136 + c*32 + q*8);
      const u32* at4 = (const u32*)&atv;
      const u32* ca4 = (const u32*)&ca8[c];
      const u32* wa4 = (const u32*)&wa8[c];
      #pragma unroll
      for (int jj=0;jj<4;jj++){
        float2 a2 = bfp2(at4[jj]);
        float2 c2 = bfp2(ca4[jj]);
        float2 w2 = bfp2(wa4[jj]);
        s += fmaxf(a2.x + c2.x, 0.f)*w2.x + fmaxf(a2.y + c2.y, 0.f)*w2.y;
      }
    }
    s += __shfl_xor(s, 16);
    s += __shfl_xor(s, 32);
    float ea = __expf(s + bal);
    // ---- scatter: row-uniform per edge (lane l owns cols 2l,2l+1) ----
    #pragma unroll
    for (int e=0;e<16;e++){
      int eg2 = it*64 + w*16 + e;
      if (eg2 < E){
        int obj_e  = __shfl(obj, e);
        float eav  = __shfl(ea, e);
        float2 m2 = bfp2(*(const u32*)(mw + e*136 + c0));
        float* ap = agg + (size_t)obj_e*D;
        atomicAdd(ap + c0,     eav*m2.x);
        atomicAdd(ap + c0 + 1, eav*m2.y);
        if (l == 0){
          atomicAdd(sum_exp + obj_e, eav);
          atomicMax(last_edge + obj_e, eg2);
        }
      }
    }
  }
}

// ---------------- finalize (4-node batched, dual output format) ----------------
__global__ __launch_bounds__(256) void final_kernel(
  const float* __restrict__ agg, const float* __restrict__ sum_exp,
  const int* __restrict__ last_edge, const int* __restrict__ edges,
  const ushort_t* __restrict__ hq_tab, const ushort_t* __restrict__ Wh,
  const int* __restrict__ flag, void* __restrict__ out_base, int N)
{
  __shared__ float mb[4][D][4];
  int tid = threadIdx.x, w = tid >> 6, l = tid & 63;
  int c0 = 2*l, c1 = c0+1;
  int isf = *flag;
  float* out0f = (float*)out_base;
  float* out1f = out0f + (size_t)N*D;
  ushort_t* out0h = (ushort_t*)out_base;
  ushort_t* out1h = out0h + (size_t)N*D;
  int nIter = (N + 15) >> 4;
  for (int it = blockIdx.x; it < nIter; it += gridDim.x){
    int base = it*16 + w*4;
    int rq[4];
    #pragma unroll
    for (int e=0;e<4;e++){
      int n = base + e; if (n >= N) n = N-1;
      float se = sum_exp[n];
      float inv = (se > 0.f) ? (1.0f/se) : 0.f;
      float2 m = *(const float2*)(agg + (size_t)n*D + c0);
      mb[w][c0][e] = m.x*inv; mb[w][c1][e] = m.y*inv;
      int le = last_edge[n];
      rq[e] = (le >= 0) ? edges[(size_t)le*6] : 0;
    }
    float a0[4] = {0,0,0,0}, a1[4] = {0,0,0,0};
    #pragma unroll 4
    for (int kp=0; kp<64; kp++){
      float4 ma = *(float4*)&mb[w][2*kp][0];
      float4 mv = *(float4*)&mb[w][2*kp+1][0];
      float2 u0 = bfp2(*(const u32*)(Wh + (2*kp)*D + c0));
      float2 u1 = bfp2(*(const u32*)(Wh + (2*kp+1)*D + c0));
      a0[0] += ma.x*u0.x + mv.x*u1.x;  a1[0] += ma.x*u0.y + mv.x*u1.y;
      a0[1] += ma.y*u0.x + mv.y*u1.x;  a1[1] += ma.y*u0.y + mv.y*u1.y;
      a0[2] += ma.z*u0.x + mv.z*u1.x;  a1[2] += ma.z*u0.y + mv.z*u1.y;
      a0[3] += ma.w*u0.x + mv.w*u1.x;  a1[3] += ma.w*u0.y + mv.w*u1.y;
    }
    #pragma unroll
    for (int e=0;e<4;e++){
      int n = base + e; if (n >= N) continue;
      float r0 = fmaxf(a0[e], 0.f), r1 = fmaxf(a1[e], 0.f);
      u32 hqw = *(const u32*)(hq_tab + (size_t)rq[e]*D + c0);
      if (isf){
        float2 o0; o0.x = r0; o0.y = r1;
        *(float2*)(out0f + (size_t)n*D + c0) = o0;
        float2 hv = bfp2(hqw);
        *(float2*)(out1f + (size_t)n*D + c0) = hv;
      } else {
        *(u32*)(out0h + (size_t)n*D + c0) = packbf(r0, r1);
        *(u32*)(out1h + (size_t)n*D + c0) = hqw;
      }
    }
  }
}

extern "C" void kernel_launch(void* const* d_in, const int* in_sizes, int n_in,
                              void* d_out, int out_size, void* d_ws, size_t ws_size,
                              hipStream_t stream)
{
  const int* q_rel = (const int*)d_in[17];
  const int* edges = (const int*)d_in[18];

  int N   = in_sizes[0]/D;
  int NRE = in_sizes[1]/D;
  int NQ  = in_sizes[17];
  int E   = in_sizes[18]/6;

  char* ws = (char*)d_ws;
  size_t o = 0;
  auto alloc = [&](size_t bytes)->void*{
    void* p = ws + o; o += (bytes + 255) & ~(size_t)255; return p;
  };
  float* agg      = (float*)alloc((size_t)N*D*4);
  float* sum_exp  = (float*)alloc((size_t)N*4);
  int*   lastedge = (int*)  alloc((size_t)N*4);
  int*   flag     = (int*)  alloc(256);

  ushort_t* canon[17];
  for (int i=0;i<17;i++) canon[i] = (ushort_t*)alloc((size_t)in_sizes[i]*2);

  ushort_t* hq_tab = (ushort_t*)alloc((size_t)NQ*D*2);
  ushort_t* Az = (ushort_t*)alloc((size_t)NRE*D*2);
  ushort_t* Ar = (ushort_t*)alloc((size_t)NRE*D*2);
  ushort_t* Ah = (ushort_t*)alloc((size_t)NRE*D*2);
  ushort_t* Bz = (ushort_t*)alloc((size_t)NQ*D*2);
  ushort_t* Br = (ushort_t*)alloc((size_t)NQ*D*2);
  ushort_t* Bh = (ushort_t*)alloc((size_t)NQ*D*2);
  ushort_t* Ca = (ushort_t*)alloc((size_t)NQ*D*2);
  ushort_t* HUz = (ushort_t*)alloc((size_t)N*D*2);
  ushort_t* HUr = (ushort_t*)alloc((size_t)N*D*2);
  ushort_t* UhF = (ushort_t*)alloc((size_t)D*D*2);
  ushort_t* WsF = (ushort_t*)alloc((size_t)D*D*2);

  CvtArgs ca;
  for (int i=0;i<17;i++){ ca.src[i]=d_in[i]; ca.dst[i]=canon[i]; ca.n[i]=in_sizes[i]; }

  const ushort_t* hidden = canon[0];
  const ushort_t* rela   = canon[1];
  const ushort_t* Wz  = canon[2];
  const ushort_t* Uz  = canon[3];
  const ushort_t* bz  = canon[4];
  const ushort_t* Wr  = canon[5];
  const ushort_t* Ur  = canon[6];
  const ushort_t* br  = canon[7];
  const ushort_t* Whh = canon[8];
  const ushort_t* Uh  = canon[9];
  const ushort_t* bh  = canon[10];
  const ushort_t* Ws  = canon[11];
  const ushort_t* Wqr = canon[12];
  const ushort_t* bqr = canon[13];
  const ushort_t* wal = canon[14];
  const ushort_t* bal = canon[15];
  const ushort_t* W_h = canon[16];

  detect_kernel<<<1, 64, 0, stream>>>((const u32*)d_in[1], flag);
  convert_kernel<<<1024, 256, 0, stream>>>(ca, flag);
  init_kernel<<<4096, 256, 0, stream>>>(agg, sum_exp, lastedge, N);
  fragorder_kernel<<<128, 256, 0, stream>>>(Uh, Ws, UhF, WsF);
  table_kernel<<<NRE+NQ, 128, 0, stream>>>(rela, Wz, Wr, Whh, Wqr, bz, br, bh, bqr,
                                           q_rel, hq_tab, Az, Ar, Ah, Bz, Br, Bh, Ca, NRE, NQ);
  hu_kernel<<<1024, 256, 0, stream>>>(hidden, Uz, Ur, HUz, HUr, N);
  edge_kernel<<<2048, 256, 0, stream>>>(edges, hidden, HUz, HUr, Az, Ar, Ah, Bz, Br, Bh, Ca,
                                        UhF, WsF, wal, bal, agg, sum_exp, lastedge, E);
  final_kernel<<<1024, 256, 0, stream>>>(agg, sum_exp, lastedge, edges, hq_tab, W_h,
                                         flag, d_out, N);
}

// Round 6
// 1442.773 us; speedup vs baseline: 1.9218x; 1.0815x over previous
//
#include <hip/hip_runtime.h>
#include <hip/hip_bf16.h>

#define D 128

typedef unsigned int u32;
typedef unsigned short ushort_t;
typedef __attribute__((ext_vector_type(8))) short short8;
typedef __attribute__((ext_vector_type(4))) float f32x4;

__device__ __forceinline__ float bf2f(ushort_t u){ return __uint_as_float(((u32)u)<<16); }
__device__ __forceinline__ ushort_t f2bf(float f){
  u32 x = __float_as_uint(f);
  return (ushort_t)((x + 0x7fffu + ((x>>16)&1u)) >> 16);
}
__device__ __forceinline__ float2 bfp2(u32 w){
  float2 r; r.x = __uint_as_float(w<<16); r.y = __uint_as_float(w & 0xffff0000u); return r;
}
__device__ __forceinline__ u32 packbf(float a, float b){
  return (u32)f2bf(a) | ((u32)f2bf(b)<<16);
}
__device__ __forceinline__ float sigm(float x){ return 1.0f/(1.0f+__expf(-x)); }
__device__ __forceinline__ float ftanh(float x){
  float e = __expf(-2.0f*fabsf(x));
  float t = (1.0f-e)/(1.0f+e);
  return copysignf(t,x);
}

// ---------------- dtype probe (f32 vs bf16 storage) ----------------
__global__ void detect_kernel(const u32* __restrict__ words, int* flag){
  int t = threadIdx.x;
  int cnt = 0;
  for (int i = t; i < 512; i += 64){
    u32 w = words[i];
    u32 e = (w >> 7) & 0xFFu;
    if (e >= 100u && e <= 126u) cnt++;
  }
  #pragma unroll
  for (int off = 32; off > 0; off >>= 1) cnt += __shfl_xor(cnt, off);
  if (t == 0) *flag = (cnt < 256) ? 1 : 0;
}

// ---------------- canonicalize all float inputs to bf16 ----------------
struct CvtArgs { const void* src[17]; ushort_t* dst[17]; int n[17]; };

__global__ __launch_bounds__(256) void convert_kernel(CvtArgs a, const int* __restrict__ flag){
  int isf = *flag;
  int gid = blockIdx.x*blockDim.x + threadIdx.x;
  int gs  = gridDim.x*blockDim.x;
  for (int s = 0; s < 17; s++){
    int n = a.n[s];
    ushort_t* dst = a.dst[s];
    int n4 = n >> 2;
    if (isf){
      const float* src = (const float*)a.src[s];
      for (int j = gid; j < n4; j += gs){
        float4 v = *(const float4*)(src + 4*j);
        uint2 o; o.x = packbf(v.x, v.y); o.y = packbf(v.z, v.w);
        *(uint2*)(dst + 4*j) = o;
      }
      for (int j = 4*n4 + gid; j < n; j += gs) dst[j] = f2bf(src[j]);
    } else {
      const ushort_t* src = (const ushort_t*)a.src[s];
      for (int j = gid; j < n4; j += gs)
        *(uint2*)(dst + 4*j) = *(const uint2*)(src + 4*j);
      for (int j = 4*n4 + gid; j < n; j += gs) dst[j] = src[j];
    }
  }
}

// ---------------- init ----------------
__global__ __launch_bounds__(256) void init_kernel(float* agg, float* sum_exp, int* last_edge, int N){
  int i = blockIdx.x*blockDim.x + threadIdx.x;
  int stride = gridDim.x*blockDim.x;
  float4 z4; z4.x=0.f; z4.y=0.f; z4.z=0.f; z4.w=0.f;
  int n4 = (N*D) >> 2;
  for (int j=i; j<n4; j+=stride) ((float4*)agg)[j] = z4;
  for (int j=i; j<N;  j+=stride){ sum_exp[j]=0.f; last_edge[j]=-1; }
}

// ---------------- per-rel and per-query tables ----------------
__global__ void table_kernel(const ushort_t* __restrict__ rela,
  const ushort_t* __restrict__ Wz, const ushort_t* __restrict__ Wr, const ushort_t* __restrict__ Wh,
  const ushort_t* __restrict__ Wqr,
  const ushort_t* __restrict__ bz, const ushort_t* __restrict__ br, const ushort_t* __restrict__ bh,
  const ushort_t* __restrict__ bqr,
  const int* __restrict__ q_rel,
  ushort_t* hq_tab, ushort_t* Az, ushort_t* Ar, ushort_t* Ah,
  ushort_t* Bz, ushort_t* Br, ushort_t* Bh, ushort_t* Ca, int NRE, int NQ)
{
  __shared__ float hrow[D];
  int d = threadIdx.x;
  int b = blockIdx.x;
  if (b < NRE) {
    const ushort_t* row = rela + (size_t)b*D;
    hrow[d] = bf2f(row[d]);
    __syncthreads();
    float az=0.f, ar=0.f, ah=0.f;
    for (int k=0;k<D;k++){
      float h = hrow[k];
      az += h*bf2f(Wz[k*D+d]);
      ar += h*bf2f(Wr[k*D+d]);
      ah += h*bf2f(Wh[k*D+d]);
    }
    Az[b*D+d]=f2bf(az); Ar[b*D+d]=f2bf(ar); Ah[b*D+d]=f2bf(ah);
  } else {
    int q = b - NRE; if (q >= NQ) return;
    int rq = q_rel[q];
    const ushort_t* row = rela + (size_t)rq*D;
    hrow[d] = bf2f(row[d]);
    hq_tab[q*D+d] = row[d];
    __syncthreads();
    float vz=bf2f(bz[d]), vr=bf2f(br[d]), vh=bf2f(bh[d]), vc=bf2f(bqr[d]);
    for (int k=0;k<D;k++){
      float h = hrow[k];
      vz += h*bf2f(Wz[(D+k)*D+d]);
      vr += h*bf2f(Wr[(D+k)*D+d]);
      vh += h*bf2f(Wh[(D+k)*D+d]);
      vc += h*bf2f(Wqr[k*D+d]);
    }
    Bz[q*D+d]=f2bf(vz); Br[q*D+d]=f2bf(vr); Bh[q*D+d]=f2bf(vh); Ca[q*D+d]=f2bf(vc);
  }
}

// ---------------- HU = hidden @ Uz, hidden @ Ur ----------------
__global__ __launch_bounds__(256) void hu_kernel(const ushort_t* __restrict__ hidden,
  const ushort_t* __restrict__ Uz, const ushort_t* __restrict__ Ur,
  ushort_t* __restrict__ HUz, ushort_t* __restrict__ HUr, int N)
{
  int l = threadIdx.x & 63;
  int gw = (int)((blockIdx.x * blockDim.x + threadIdx.x) >> 6);
  int nw = (int)((gridDim.x * blockDim.x) >> 6);
  int c0 = 2*l;
  for (int n = gw; n < N; n += nw) {
    float2 h = bfp2(*(const u32*)(hidden + (size_t)n*D + c0));
    float az0=0.f,az1=0.f,ar0=0.f,ar1=0.f;
    #pragma unroll 4
    for (int kp=0; kp<64; kp++) {
      float hx = __shfl(h.x, kp);
      float hy = __shfl(h.y, kp);
      float2 uz0 = bfp2(*(const u32*)(Uz + (2*kp)*D + c0));
      float2 uz1 = bfp2(*(const u32*)(Uz + (2*kp+1)*D + c0));
      float2 ur0 = bfp2(*(const u32*)(Ur + (2*kp)*D + c0));
      float2 ur1 = bfp2(*(const u32*)(Ur + (2*kp+1)*D + c0));
      az0 += hx*uz0.x + hy*uz1.x;
      az1 += hx*uz0.y + hy*uz1.y;
      ar0 += hx*ur0.x + hy*ur1.x;
      ar1 += hx*ur0.y + hy*ur1.y;
    }
    *(u32*)(HUz + (size_t)n*D + c0) = packbf(az0, az1);
    *(u32*)(HUr + (size_t)n*D + c0) = packbf(ar0, ar1);
  }
}

// ---------------- fragment-order Uh and Ws for MFMA B-operand ----------------
__global__ void fragorder_kernel(const ushort_t* __restrict__ Uh, const ushort_t* __restrict__ Ws,
                                 ushort_t* __restrict__ UhF, ushort_t* __restrict__ WsF){
  int idx = blockIdx.x*blockDim.x + threadIdx.x;
  if (idx >= 2*D*D) return;
  int which = idx >> 14;
  int i = idx & 16383;
  int j = i & 7;
  int l = (i >> 3) & 63;
  int ct = i >> 9;
  int c = ct >> 3, t = ct & 7;
  int k = c*32 + (l>>4)*8 + j;
  int n = t*16 + (l&15);
  ushort_t v = (which ? Ws : Uh)[k*D + n];
  if (which) WsF[i] = v; else UhF[i] = v;
}

// ---------------- main per-edge kernel ----------------
// Wave owns 16 edges. Gather is COALESCED col-owner (lane l owns col 2l of one
// table row per instruction; per-edge indices broadcast via shfl) -> v,z,hs
// staged in wave-private LDS. MFMA phases read A-frags from LDS. Scatter is
// row-uniform (R2 pattern). Small rel/ridx-indexed tables (L2-resident) are
// read scattered in A-layout where convenient.
__global__ __launch_bounds__(256, 3) void edge_kernel(
  const int* __restrict__ edges,
  const ushort_t* __restrict__ hidden,
  const ushort_t* __restrict__ HUz, const ushort_t* __restrict__ HUr,
  const ushort_t* __restrict__ Az, const ushort_t* __restrict__ Ar, const ushort_t* __restrict__ Ah,
  const ushort_t* __restrict__ Bz, const ushort_t* __restrict__ Br, const ushort_t* __restrict__ Bh,
  const ushort_t* __restrict__ Ca,
  const ushort_t* __restrict__ UhF, const ushort_t* __restrict__ WsF,
  const ushort_t* __restrict__ w_alpha, const ushort_t* __restrict__ b_alpha,
  float* __restrict__ agg, float* __restrict__ sum_exp, int* __restrict__ last_edge,
  int E)
{
  __shared__ __align__(16) ushort_t vb[4][16*136];  // v -> AC-trans -> ATT-trans
  __shared__ __align__(16) ushort_t zb[4][16*136];  // z -> m
  __shared__ __align__(16) ushort_t hb[4][16*136];  // hs
  int tid = threadIdx.x;
  int w = tid>>6, l = tid&63;
  int l15 = l & 15, q = l >> 4;
  int c0 = 2*l;
  ushort_t* V = &vb[w][0];
  ushort_t* Z = &zb[w][0];
  ushort_t* H = &hb[w][0];
  float bal = bf2f(b_alpha[0]);

  int nIter = (E + 63) >> 6;
  for (int it = blockIdx.x; it < nIter; it += gridDim.x) {
    int ebase = it*64 + w*16;
    int eraw = ebase + l15;
    int eg = (eraw < E) ? eraw : (E-1);
    const int* ep = edges + (size_t)eg*6;
    int ridx = ep[0], rel = ep[2], sub = ep[4], obj = ep[5];

    // ---- coalesced gather, col-owner; stage v,z,hs to LDS ----
    #pragma unroll 4
    for (int e=0;e<16;e++){
      int rel_e  = __shfl(rel, e);
      int ridx_e = __shfl(ridx, e);
      int sub_e  = __shfl(sub, e);
      float2 az = bfp2(*(const u32*)(Az + (size_t)rel_e*D + c0));
      float2 bz = bfp2(*(const u32*)(Bz + (size_t)ridx_e*D + c0));
      float2 hz = bfp2(*(const u32*)(HUz + (size_t)sub_e*D + c0));
      float2 ar = bfp2(*(const u32*)(Ar + (size_t)rel_e*D + c0));
      float2 br = bfp2(*(const u32*)(Br + (size_t)ridx_e*D + c0));
      float2 hr = bfp2(*(const u32*)(HUr + (size_t)sub_e*D + c0));
      float2 hs = bfp2(*(const u32*)(hidden + (size_t)sub_e*D + c0));
      float z0 = sigm(az.x+bz.x+hz.x), z1 = sigm(az.y+bz.y+hz.y);
      float r0 = sigm(ar.x+br.x+hr.x), r1 = sigm(ar.y+br.y+hr.y);
      *(u32*)(V + e*136 + c0) = packbf(r0*hs.x, r1*hs.y);
      *(u32*)(Z + e*136 + c0) = packbf(z0, z1);
      *(u32*)(H + e*136 + c0) = packbf(hs.x, hs.y);
    }
    __builtin_amdgcn_wave_barrier();
    // ---- A-phase reads from LDS (A-frag layout) ----
    short8 af[4], z8[4], h8[4];
    #pragma unroll
    for (int c=0;c<4;c++){
      af[c] = *(const short8*)(V + l15*136 + c*32 + q*8);
      z8[c] = *(const short8*)(Z + l15*136 + c*32 + q*8);
      h8[c] = *(const short8*)(H + l15*136 + c*32 + q*8);
    }
    // ---- matvec1: AC[16x128] = (r*hs) @ Uh ----
    f32x4 zero = {0.f,0.f,0.f,0.f};
    f32x4 acc[8];
    #pragma unroll
    for (int t=0;t<8;t++) acc[t] = zero;
    #pragma unroll
    for (int t=0;t<8;t++){
      #pragma unroll
      for (int c=0;c<4;c++){
        short8 bf = *(const short8*)(UhF + ((size_t)((c*8+t)*64 + l))*8);
        acc[t] = __builtin_amdgcn_mfma_f32_16x16x32_bf16(af[c], bf, acc[t], 0,0,0);
      }
    }
    __builtin_amdgcn_wave_barrier();
    // ---- transpose AC: C/D -> edge-row layout in V ----
    #pragma unroll
    for (int t=0;t<8;t++){
      #pragma unroll
      for (int r=0;r<4;r++){
        float x = acc[t][r];
        float y = __shfl_xor(x, 1);
        if (!(l & 1))
          *(u32*)(V + (q*4+r)*136 + t*16 + l15) = packbf(x, y);
      }
    }
    // ab = Ah[rel]+Bh[ridx], scattered A-layout (small L2-hot tables)
    short8 ah8[4], bh8[4];
    #pragma unroll
    for (int c=0;c<4;c++){
      ah8[c] = *(const short8*)(Ah + (size_t)rel*D + c*32 + q*8);
      bh8[c] = *(const short8*)(Bh + (size_t)ridx*D + c*32 + q*8);
    }
    __builtin_amdgcn_wave_barrier();
    // ---- gate: m = (1-z)*hs + z*tanh(ac+ab); af <- m; m -> Z (edge-row) ----
    #pragma unroll
    for (int c=0;c<4;c++){
      short8 acv = *(const short8*)(V + l15*136 + c*32 + q*8);
      const u32* ac4 = (const u32*)&acv;
      const u32* ah4 = (const u32*)&ah8[c];
      const u32* bh4 = (const u32*)&bh8[c];
      const u32* z4  = (const u32*)&z8[c];
      const u32* h4  = (const u32*)&h8[c];
      u32 mv[4];
      #pragma unroll
      for (int jj=0;jj<4;jj++){
        float2 ac2 = bfp2(ac4[jj]);
        float2 a2 = bfp2(ah4[jj]), b2 = bfp2(bh4[jj]);
        float2 z2 = bfp2(z4[jj]);
        float2 h2 = bfp2(h4[jj]);
        float m0 = (1.f - z2.x)*h2.x + z2.x*ftanh(ac2.x + a2.x + b2.x);
        float m1 = (1.f - z2.y)*h2.y + z2.y*ftanh(ac2.y + a2.y + b2.y);
        mv[jj] = packbf(m0, m1);
      }
      af[c] = *(short8*)mv;
      *(short8*)(Z + l15*136 + c*32 + q*8) = af[c];
    }
    // ---- matvec2: ATT[16x128] = M @ Ws ----
    #pragma unroll
    for (int t=0;t<8;t++) acc[t] = zero;
    #pragma unroll
    for (int t=0;t<8;t++){
      #pragma unroll
      for (int c=0;c<4;c++){
        short8 bf = *(const short8*)(WsF + ((size_t)((c*8+t)*64 + l))*8);
        acc[t] = __builtin_amdgcn_mfma_f32_16x16x32_bf16(af[c], bf, acc[t], 0,0,0);
      }
    }
    __builtin_amdgcn_wave_barrier();
    // ---- transpose ATT -> V ----
    #pragma unroll
    for (int t=0;t<8;t++){
      #pragma unroll
      for (int r=0;r<4;r++){
        float x = acc[t][r];
        float y = __shfl_xor(x, 1);
        if (!(l & 1))
          *(u32*)(V + (q*4+r)*136 + t*16 + l15) = packbf(x, y);
      }
    }
    short8 ca8[4], wa8[4];
    #pragma unroll
    for (int c=0;c<4;c++){
      ca8[c] = *(const short8*)(Ca + (size_t)ridx*D + c*32 + q*8);
      wa8[c] = *(const short8*)(w_alpha + c*32 + q*8);
    }
    __builtin_amdgcn_wave_barrier();
    // ---- attn score over lane's 32 cols of edge l15 ----
    float s = 0.f;
    #pragma unroll
    for (int c=0;c<4;c++){
      short8 atv = *(const short8*)(V + l15*136 + c*32 + q*8);
      const u32* at4 = (const u32*)&atv;
      const u32* ca4 = (const u32*)&ca8[c];
      const u32* wa4 = (const u32*)&wa8[c];
      #pragma unroll
      for (int jj=0;jj<4;jj++){
        float2 a2 = bfp2(at4[jj]);
        float2 c2 = bfp2(ca4[jj]);
        float2 w2 = bfp2(wa4[jj]);
        s += fmaxf(a2.x + c2.x, 0.f)*w2.x + fmaxf(a2.y + c2.y, 0.f)*w2.y;
      }
    }
    s += __shfl_xor(s, 16);
    s += __shfl_xor(s, 32);
    float ea = __expf(s + bal);
    // ---- per-edge scalars: lanes 0..15 in parallel ----
    if (l < 16 && (ebase + l) < E){
      atomicAdd(sum_exp + obj, ea);
      atomicMax(last_edge + obj, ebase + l);
    }
    __builtin_amdgcn_wave_barrier();
    // ---- scatter m: row-uniform per edge (lane l owns cols 2l,2l+1) ----
    #pragma unroll
    for (int e=0;e<16;e++){
      int eg2 = ebase + e;
      if (eg2 < E){
        int obj_e  = __shfl(obj, e);
        float eav  = __shfl(ea, e);
        float2 m2 = bfp2(*(const u32*)(Z + e*136 + c0));
        float* ap = agg + (size_t)obj_e*D;
        atomicAdd(ap + c0,     eav*m2.x);
        atomicAdd(ap + c0 + 1, eav*m2.y);
      }
    }
  }
}

// ---------------- finalize (4-node batched, dual output format) ----------------
__global__ __launch_bounds__(256) void final_kernel(
  const float* __restrict__ agg, const float* __restrict__ sum_exp,
  const int* __restrict__ last_edge, const int* __restrict__ edges,
  const ushort_t* __restrict__ hq_tab, const ushort_t* __restrict__ Wh,
  const int* __restrict__ flag, void* __restrict__ out_base, int N)
{
  __shared__ float mb[4][D][4];
  int tid = threadIdx.x, w = tid >> 6, l = tid & 63;
  int c0 = 2*l, c1 = c0+1;
  int isf = *flag;
  float* out0f = (float*)out_base;
  float* out1f = out0f + (size_t)N*D;
  ushort_t* out0h = (ushort_t*)out_base;
  ushort_t* out1h = out0h + (size_t)N*D;
  int nIter = (N + 15) >> 4;
  for (int it = blockIdx.x; it < nIter; it += gridDim.x){
    int base = it*16 + w*4;
    int rq[4];
    #pragma unroll
    for (int e=0;e<4;e++){
      int n = base + e; if (n >= N) n = N-1;
      float se = sum_exp[n];
      float inv = (se > 0.f) ? (1.0f/se) : 0.f;
      float2 m = *(const float2*)(agg + (size_t)n*D + c0);
      mb[w][c0][e] = m.x*inv; mb[w][c1][e] = m.y*inv;
      int le = last_edge[n];
      rq[e] = (le >= 0) ? edges[(size_t)le*6] : 0;
    }
    float a0[4] = {0,0,0,0}, a1[4] = {0,0,0,0};
    #pragma unroll 4
    for (int kp=0; kp<64; kp++){
      float4 ma = *(float4*)&mb[w][2*kp][0];
      float4 mv = *(float4*)&mb[w][2*kp+1][0];
      float2 u0 = bfp2(*(const u32*)(Wh + (2*kp)*D + c0));
      float2 u1 = bfp2(*(const u32*)(Wh + (2*kp+1)*D + c0));
      a0[0] += ma.x*u0.x + mv.x*u1.x;  a1[0] += ma.x*u0.y + mv.x*u1.y;
      a0[1] += ma.y*u0.x + mv.y*u1.x;  a1[1] += ma.y*u0.y + mv.y*u1.y;
      a0[2] += ma.z*u0.x + mv.z*u1.x;  a1[2] += ma.z*u0.y + mv.z*u1.y;
      a0[3] += ma.w*u0.x + mv.w*u1.x;  a1[3] += ma.w*u0.y + mv.w*u1.y;
    }
    #pragma unroll
    for (int e=0;e<4;e++){
      int n = base + e; if (n >= N) continue;
      float r0 = fmaxf(a0[e], 0.f), r1 = fmaxf(a1[e], 0.f);
      u32 hqw = *(const u32*)(hq_tab + (size_t)rq[e]*D + c0);
      if (isf){
        float2 o0; o0.x = r0; o0.y = r1;
        *(float2*)(out0f + (size_t)n*D + c0) = o0;
        float2 hv = bfp2(hqw);
        *(float2*)(out1f + (size_t)n*D + c0) = hv;
      } else {
        *(u32*)(out0h + (size_t)n*D + c0) = packbf(r0, r1);
        *(u32*)(out1h + (size_t)n*D + c0) = hqw;
      }
    }
  }
}

extern "C" void kernel_launch(void* const* d_in, const int* in_sizes, int n_in,
                              void* d_out, int out_size, void* d_ws, size_t ws_size,
                              hipStream_t stream)
{
  const int* q_rel = (const int*)d_in[17];
  const int* edges = (const int*)d_in[18];

  int N   = in_sizes[0]/D;
  int NRE = in_sizes[1]/D;
  int NQ  = in_sizes[17];
  int E   = in_sizes[18]/6;

  char* ws = (char*)d_ws;
  size_t o = 0;
  auto alloc = [&](size_t bytes)->void*{
    void* p = ws + o; o += (bytes + 255) & ~(size_t)255; return p;
  };
  float* agg      = (float*)alloc((size_t)N*D*4);
  float* sum_exp  = (float*)alloc((size_t)N*4);
  int*   lastedge = (int*)  alloc((size_t)N*4);
  int*   flag     = (int*)  alloc(256);

  ushort_t* canon[17];
  for (int i=0;i<17;i++) canon[i] = (ushort_t*)alloc((size_t)in_sizes[i]*2);

  ushort_t* hq_tab = (ushort_t*)alloc((size_t)NQ*D*2);
  ushort_t* Az = (ushort_t*)alloc((size_t)NRE*D*2);
  ushort_t* Ar = (ushort_t*)alloc((size_t)NRE*D*2);
  ushort_t* Ah = (ushort_t*)alloc((size_t)NRE*D*2);
  ushort_t* Bz = (ushort_t*)alloc((size_t)NQ*D*2);
  ushort_t* Br = (ushort_t*)alloc((size_t)NQ*D*2);
  ushort_t* Bh = (ushort_t*)alloc((size_t)NQ*D*2);
  ushort_t* Ca = (ushort_t*)alloc((size_t)NQ*D*2);
  ushort_t* HUz = (ushort_t*)alloc((size_t)N*D*2);
  ushort_t* HUr = (ushort_t*)alloc((size_t)N*D*2);
  ushort_t* UhF = (ushort_t*)alloc((size_t)D*D*2);
  ushort_t* WsF = (ushort_t*)alloc((size_t)D*D*2);

  CvtArgs ca;
  for (int i=0;i<17;i++){ ca.src[i]=d_in[i]; ca.dst[i]=canon[i]; ca.n[i]=in_sizes[i]; }

  const ushort_t* hidden = canon[0];
  const ushort_t* rela   = canon[1];
  const ushort_t* Wz  = canon[2];
  const ushort_t* Uz  = canon[3];
  const ushort_t* bz  = canon[4];
  const ushort_t* Wr  = canon[5];
  const ushort_t* Ur  = canon[6];
  const ushort_t* br  = canon[7];
  const ushort_t* Whh = canon[8];
  const ushort_t* Uh  = canon[9];
  const ushort_t* bh  = canon[10];
  const ushort_t* Ws  = canon[11];
  const ushort_t* Wqr = canon[12];
  const ushort_t* bqr = canon[13];
  const ushort_t* wal = canon[14];
  const ushort_t* bal = canon[15];
  const ushort_t* W_h = canon[16];

  detect_kernel<<<1, 64, 0, stream>>>((const u32*)d_in[1], flag);
  convert_kernel<<<1024, 256, 0, stream>>>(ca, flag);
  init_kernel<<<2048, 256, 0, stream>>>(agg, sum_exp, lastedge, N);
  fragorder_kernel<<<128, 256, 0, stream>>>(Uh, Ws, UhF, WsF);
  table_kernel<<<NRE+NQ, 128, 0, stream>>>(rela, Wz, Wr, Whh, Wqr, bz, br, bh, bqr,
                                           q_rel, hq_tab, Az, Ar, Ah, Bz, Br, Bh, Ca, NRE, NQ);
  hu_kernel<<<1024, 256, 0, stream>>>(hidden, Uz, Ur, HUz, HUr, N);
  edge_kernel<<<2048, 256, 0, stream>>>(edges, hidden, HUz, HUr, Az, Ar, Ah, Bz, Br, Bh, Ca,
                                        UhF, WsF, wal, bal, agg, sum_exp, lastedge, E);
  final_kernel<<<1024, 256, 0, stream>>>(agg, sum_exp, lastedge, edges, hq_tab, W_h,
                                         flag, d_out, N);
}